// Round 11
// baseline (15.156 us; speedup 1.0000x reference)
//
#include <hip/hip_runtime.h>

// DWA_CNN: B=32, T=2048, C=128, K=3, F=8, P=2046
// v10: batch-paired 2-tile pipeline. Block (bx,bq) handles (b=bq,p0) and
//      (b=bq+16,p0): w staged + WN computed ONCE, x2 loads issued before
//      barrier 1 so they drain under tile-1 compute/phase2. Grid 33x16=528
//      uniform blocks (~2/CU). All v9-validated pieces (swizzled Wb, self-MFMA
//      WN, f-paired phase 2, lgkm-only barriers) unchanged.

#define TT   62
#define RWS  64
#define DSTR 68   // floats; 272 B rows, b128-aligned

typedef __attribute__((ext_vector_type(8))) short short8v;
typedef __attribute__((ext_vector_type(4))) float f32x4;

static __device__ inline unsigned pk2(float lo, float hi) {
  unsigned r;
  asm("v_cvt_pk_bf16_f32 %0, %1, %2" : "=v"(r) : "v"(lo), "v"(hi));
  return r;
}
static __device__ inline int swzi(int row, int c) {
  return row * 128 + (((c >> 3) ^ (row & 7)) << 3) + (c & 7);
}

// interior DTW cell; cands order [diag,left,up], first-min tie-break (jnp.argmin)
static __device__ inline void dpsel(float ca, float cb, float cc,
                                    float Ad, float Al, float Au,
                                    float dist, float dot,
                                    float& costv, float& Av) {
  costv = dist + fminf(fminf(ca, cb), cc);
  const bool d_le_l = (ca <= cb);
  const bool d_le_u = (ca <= cc);
  const bool l_le_u = (cb <= cc);
  Av = dot + (d_le_l ? (d_le_u ? Ad : Au) : (l_le_u ? Al : Au));
}

#define LGKM_BARRIER() asm volatile("s_waitcnt lgkmcnt(0)\n\ts_barrier" ::: "memory")

// cvt 8 float4 -> 4 A-frags + full row norm (copies in all lanes of the row group)
static __device__ inline float cvt_frags(const float4* xa, short8v* af) {
  float xn = 0.f;
  #pragma unroll
  for (int kk = 0; kk < 4; ++kk) {
    const float4 a = xa[2 * kk], c4 = xa[2 * kk + 1];
    xn = fmaf(a.x, a.x, fmaf(a.y, a.y, fmaf(a.z, a.z, fmaf(a.w, a.w, xn))));
    xn = fmaf(c4.x, c4.x, fmaf(c4.y, c4.y, fmaf(c4.z, c4.z, fmaf(c4.w, c4.w, xn))));
    uint4 pr;
    pr.x = pk2(a.x, a.y);   pr.y = pk2(a.z, a.w);
    pr.z = pk2(c4.x, c4.y); pr.w = pk2(c4.z, c4.w);
    af[kk] = *(short8v*)&pr;
  }
  xn += __shfl_xor(xn, 16);
  xn += __shfl_xor(xn, 32);
  return xn;
}

// (dot,dist) table; C/D layout: col=lane&15, row=g*4+r [m89]
static __device__ inline void write_table(float* DsG, const f32x4& a0, const f32x4& a1,
                                          float xn, float wn0, float wn1,
                                          int wave, int g, int q0) {
  const int rq = g * 4;
  #pragma unroll
  for (int r = 0; r < 4; ++r) {
    const float xnv = __shfl(xn, rq + r);        // norm of row wave*16+rq+r
    const int row = wave * 16 + rq + r;
    float2 pv0;
    pv0.x = a0[r];
    pv0.y = sqrtf(fmaxf(xnv + wn0 - 2.f * a0[r], 0.f));
    *(float2*)&DsG[row * DSTR + q0 * 2] = pv0;
    if (q0 < 8) {
      float2 pv1;
      pv1.x = a1[r];
      pv1.y = sqrtf(fmaxf(xnv + wn1 - 2.f * a1[r], 0.f));
      *(float2*)&DsG[row * DSTR + (16 + q0) * 2] = pv1;
    }
  }
}

// phase 2: thread = (pl, f-pair); 9x b128 reads serve 2 outputs
static __device__ inline void dtw_phase2(const float* DsG, const float* BI,
                                         float* __restrict__ out, int b, int p0,
                                         int tid) {
  if (tid < TT * 4) {
    const int pl = tid >> 2, f0 = (tid & 3) * 2;

    float d0[3][3], s0[3][3], d1[3][3], s1[3][3];
    #pragma unroll
    for (int i = 0; i < 3; ++i) {
      #pragma unroll
      for (int k = 0; k < 3; ++k) {
        const float4 pr = *(const float4*)&DsG[(pl + i) * DSTR + (k * 8 + f0) * 2];
        d0[i][k] = pr.x; s0[i][k] = pr.y;   // f0
        d1[i][k] = pr.z; s1[i][k] = pr.w;   // f0+1
      }
    }

    float2 o;
    {
      const float c11 = s0[0][0];
      const float c12 = c11 + s0[0][1];
      const float c13 = c12 + s0[0][2];
      const float c21 = c11 + s0[1][0];
      const float c31 = c21 + s0[2][0];
      const float A11 = d0[0][0];
      const float A12 = A11 + d0[0][1];
      const float A13 = A12 + d0[0][2];
      const float A21 = A11 + d0[1][0];
      const float A31 = A21 + d0[2][0];
      float c22, A22, c23, A23, c32, A32, cxx, A33;
      dpsel(c11, c21, c12, A11, A21, A12, s0[1][1], d0[1][1], c22, A22);
      dpsel(c12, c22, c13, A12, A22, A13, s0[1][2], d0[1][2], c23, A23);
      dpsel(c21, c31, c22, A21, A31, A22, s0[2][1], d0[2][1], c32, A32);
      dpsel(c22, c32, c23, A22, A32, A23, s0[2][2], d0[2][2], cxx, A33);
      o.x = fmaxf(A33 + BI[f0], 0.f);
    }
    {
      const float c11 = s1[0][0];
      const float c12 = c11 + s1[0][1];
      const float c13 = c12 + s1[0][2];
      const float c21 = c11 + s1[1][0];
      const float c31 = c21 + s1[2][0];
      const float A11 = d1[0][0];
      const float A12 = A11 + d1[0][1];
      const float A13 = A12 + d1[0][2];
      const float A21 = A11 + d1[1][0];
      const float A31 = A21 + d1[2][0];
      float c22, A22, c23, A23, c32, A32, cxx, A33;
      dpsel(c11, c21, c12, A11, A21, A12, s1[1][1], d1[1][1], c22, A22);
      dpsel(c12, c22, c13, A12, A22, A13, s1[1][2], d1[1][2], c23, A23);
      dpsel(c21, c31, c22, A21, A31, A22, s1[2][1], d1[2][1], c32, A32);
      dpsel(c22, c32, c23, A22, A32, A23, s1[2][2], d1[2][2], cxx, A33);
      o.y = fmaxf(A33 + BI[f0 + 1], 0.f);
    }

    *(float2*)&out[((size_t)b * 2046 + p0 + pl) * 8 + f0] = o;
  }
}

__global__ __launch_bounds__(256, 4) void dwa_cnn_kernel(
    const float* __restrict__ x, const float* __restrict__ w,
    const float* __restrict__ bias, float* __restrict__ out)
{
  constexpr int T = 2048, C = 128;

  __shared__ alignas(16) unsigned short Wb[32 * 128];  // 8 KB (rows 24..31 zero)
  __shared__ alignas(16) float DsG[RWS * DSTR];        // 17.4 KB (dot,dist) pairs
  __shared__ float BI[8];

  const int tid  = threadIdx.x;
  const int bq   = blockIdx.y;           // batch pair: b and b+16
  const int p0   = blockIdx.x * TT;      // 33*62 = 2046 exact; rows <= 2047
  const int wave = tid >> 6;
  const int lane = tid & 63;
  const int g    = lane >> 4, l15 = lane & 15;
  const int arow = wave * 16 + l15;

  // ---- 1) w loads first (oldest in vmcnt queue -> staging never waits on x) ----
  float4 wv[3];
  #pragma unroll
  for (int j = 0; j < 3; ++j)
    wv[j] = *(const float4*)&w[j * 1024 + tid * 4];
  const float breg = (tid < 8) ? bias[tid] : 0.f;

  // ---- 2) tile-1 x loads (b = bq) ----
  const float* xr1 = &x[((size_t)bq * T + p0 + arow) * C + g * 8];
  float4 xa[8];
  #pragma unroll
  for (int kk = 0; kk < 4; ++kk) {
    xa[2 * kk]     = *(const float4*)(xr1 + kk * 32);
    xa[2 * kk + 1] = *(const float4*)(xr1 + kk * 32 + 4);
  }

  // ---- 3) stage w -> Wb (bf16, swizzled); consumes wv ----
  #pragma unroll
  for (int j = 0; j < 3; ++j) {
    const int i4 = j * 1024 + tid * 4;     // i = k*1024 + c*8 + f
    const int k = i4 >> 10, c = (i4 >> 3) & 127, f0 = i4 & 7;
    const int q = k * 8 + f0;
    Wb[swzi(q + 0, c)] = (unsigned short)pk2(wv[j].x, wv[j].x);
    Wb[swzi(q + 1, c)] = (unsigned short)pk2(wv[j].y, wv[j].y);
    Wb[swzi(q + 2, c)] = (unsigned short)pk2(wv[j].z, wv[j].z);
    Wb[swzi(q + 3, c)] = (unsigned short)pk2(wv[j].w, wv[j].w);
  }
  { uint2 z = {0u, 0u}; *(uint2*)&Wb[3072 + tid * 4] = z; }  // rows 24..31 = 0
  if (tid < 8) BI[tid] = breg;

  // ---- 4) tile-2 x loads (b = bq+16), issued BEFORE barrier -> in flight ----
  const float* xr2 = &x[(((size_t)bq + 16) * T + p0 + arow) * C + g * 8];
  float4 xb[8];
  #pragma unroll
  for (int kk = 0; kk < 4; ++kk) {
    xb[2 * kk]     = *(const float4*)(xr2 + kk * 32);
    xb[2 * kk + 1] = *(const float4*)(xr2 + kk * 32 + 4);
  }

  // barrier 1: publish Wb/BI (LDS only) -- all x loads stay in flight
  LGKM_BARRIER();

  // ---- 5) tile-1 cvt + norm ----
  short8v af[4];
  const float xn1 = cvt_frags(xa, af);

  // ---- 6) B-frags (live across both tiles) ----
  const int q0 = l15;
  short8v b0f[4], b1f[4];
  #pragma unroll
  for (int kk = 0; kk < 4; ++kk) {
    const int oct = kk * 4 + g;
    b0f[kk] = *(const short8v*)&Wb[swzi(q0,      oct * 8)];
    b1f[kk] = *(const short8v*)&Wb[swzi(q0 + 16, oct * 8)];
  }

  // ---- 7) MFMA tile-1 + WN self-products (once per block) ----
  f32x4 acc0 = {0.f, 0.f, 0.f, 0.f}, acc1 = {0.f, 0.f, 0.f, 0.f};
  f32x4 aw0  = {0.f, 0.f, 0.f, 0.f}, aw1  = {0.f, 0.f, 0.f, 0.f};
  #pragma unroll
  for (int kk = 0; kk < 4; ++kk) {
    acc0 = __builtin_amdgcn_mfma_f32_16x16x32_bf16(af[kk], b0f[kk], acc0, 0, 0, 0);
    acc1 = __builtin_amdgcn_mfma_f32_16x16x32_bf16(af[kk], b1f[kk], acc1, 0, 0, 0);
    aw0  = __builtin_amdgcn_mfma_f32_16x16x32_bf16(b0f[kk], b0f[kk], aw0, 0, 0, 0);
    aw1  = __builtin_amdgcn_mfma_f32_16x16x32_bf16(b1f[kk], b1f[kk], aw1, 0, 0, 0);
  }

  // ---- 8) WN[q] = diag of aw: value at lane ((q>>2)<<4)|q, reg q&3 ----
  float wn0, wn1;
  {
    const int src = ((l15 >> 2) << 4) | l15;
    const int rsel = l15 & 3;
    float s0 = __shfl(aw0[0], src), s1 = __shfl(aw0[1], src);
    float s2 = __shfl(aw0[2], src), s3 = __shfl(aw0[3], src);
    wn0 = (rsel == 0) ? s0 : (rsel == 1) ? s1 : (rsel == 2) ? s2 : s3;
    s0 = __shfl(aw1[0], src); s1 = __shfl(aw1[1], src);
    s2 = __shfl(aw1[2], src); s3 = __shfl(aw1[3], src);
    wn1 = (rsel == 0) ? s0 : (rsel == 1) ? s1 : (rsel == 2) ? s2 : s3;
  }

  // ---- 9) table tile-1 ----
  write_table(DsG, acc0, acc1, xn1, wn0, wn1, wave, g, q0);

  // barrier 2: publish DsG(t1)
  LGKM_BARRIER();

  // ---- 10) phase 2 tile-1 (tile-2 x drains under this) ----
  dtw_phase2(DsG, BI, out, bq, p0, tid);

  // barrier 3: all t1 reads retired -> DsG reusable
  LGKM_BARRIER();

  // ---- 11) tile-2 cvt + MFMA (B-frags & WN reused) ----
  short8v af2[4];
  const float xn2 = cvt_frags(xb, af2);
  f32x4 e0 = {0.f, 0.f, 0.f, 0.f}, e1 = {0.f, 0.f, 0.f, 0.f};
  #pragma unroll
  for (int kk = 0; kk < 4; ++kk) {
    e0 = __builtin_amdgcn_mfma_f32_16x16x32_bf16(af2[kk], b0f[kk], e0, 0, 0, 0);
    e1 = __builtin_amdgcn_mfma_f32_16x16x32_bf16(af2[kk], b1f[kk], e1, 0, 0, 0);
  }

  // ---- 12) table tile-2 ----
  write_table(DsG, e0, e1, xn2, wn0, wn1, wave, g, q0);

  // barrier 4: publish DsG(t2)
  LGKM_BARRIER();

  // ---- 13) phase 2 tile-2 ----
  dtw_phase2(DsG, BI, out, bq + 16, p0, tid);
}

extern "C" void kernel_launch(void* const* d_in, const int* in_sizes, int n_in,
                              void* d_out, int out_size, void* d_ws, size_t ws_size,
                              hipStream_t stream) {
  const float* x    = (const float*)d_in[0];
  const float* w    = (const float*)d_in[1];
  const float* bias = (const float*)d_in[2];
  float* out        = (float*)d_out;

  dim3 grid(33, 16);   // 33 p-tiles x 16 batch-pairs = 528 blocks, 2 tiles each
  dwa_cnn_kernel<<<grid, 256, 0, stream>>>(x, w, bias, out);
}

// Round 12
// 13.475 us; speedup vs baseline: 1.1247x; 1.1247x over previous
//
#include <hip/hip_runtime.h>

// DWA_CNN: B=32, T=2048, C=128, K=3, F=8, P=2046
// v11: wave-decoupled. Wave w owns rows p0+w*14..+15 (overlap: rows shared by
//      adjacent waves recomputed, +9% MFMA) and produces the 14 contained
//      outputs. (dot,dist) table lives in a WAVE-PRIVATE LDS slice; same-wave
//      write->read needs only lgkmcnt (compiler-inserted), no __syncthreads.
//      ONE barrier total (Wb publish); after it, waves are fully independent
//      -> a straggler wave no longer stalls the other 3 (v9's barrier 2 did).

#define TT    56      // outputs per block = 4 waves * 14
#define WOUT  14      // outputs per wave
#define TSTR  52      // table row stride (floats): 16B-aligned, 20*row%32 spreads banks

typedef __attribute__((ext_vector_type(8))) short short8v;
typedef __attribute__((ext_vector_type(4))) float f32x4;

static __device__ inline unsigned pk2(float lo, float hi) {
  unsigned r;
  asm("v_cvt_pk_bf16_f32 %0, %1, %2" : "=v"(r) : "v"(lo), "v"(hi));
  return r;
}
static __device__ inline int swzi(int row, int c) {
  return row * 128 + (((c >> 3) ^ (row & 7)) << 3) + (c & 7);
}

// interior DTW cell; cands order [diag,left,up], first-min tie-break (jnp.argmin)
static __device__ inline void dpsel(float ca, float cb, float cc,
                                    float Ad, float Al, float Au,
                                    float dist, float dot,
                                    float& costv, float& Av) {
  costv = dist + fminf(fminf(ca, cb), cc);
  const bool d_le_l = (ca <= cb);
  const bool d_le_u = (ca <= cc);
  const bool l_le_u = (cb <= cc);
  Av = dot + (d_le_l ? (d_le_u ? Ad : Au) : (l_le_u ? Al : Au));
}

__global__ __launch_bounds__(256, 4) void dwa_cnn_kernel(
    const float* __restrict__ x, const float* __restrict__ w,
    const float* __restrict__ bias, float* __restrict__ out)
{
  constexpr int T = 2048, C = 128, P = 2046;

  __shared__ alignas(16) unsigned short Wb[32 * 128];   // 8 KB (rows 24..31 zero)
  __shared__ alignas(16) float TB[4][16 * TSTR];        // 13.3 KB wave-private tables
  __shared__ float BI[8];

  const int tid  = threadIdx.x;
  const int b    = blockIdx.y;
  const int p0   = blockIdx.x * TT;
  const int wave = tid >> 6;
  const int lane = tid & 63;
  const int g    = lane >> 4, l15 = lane & 15;

  // this wave's global row for the A-fragment (clamped; excess outputs masked)
  const int trow0 = p0 + wave * WOUT + l15;
  const int trow  = (trow0 < T) ? trow0 : (T - 1);

  // ---- 1) w loads first (oldest in vmcnt queue) ----
  float4 wv[3];
  #pragma unroll
  for (int j = 0; j < 3; ++j)
    wv[j] = *(const float4*)&w[j * 1024 + tid * 4];
  const float breg = (tid < 8) ? bias[tid] : 0.f;

  // ---- 2) x loads (8 dwordx4, 2 contiguous per k-step) ----
  const float* xr = &x[((size_t)b * T + trow) * C + g * 8];
  float4 xa[8];
  #pragma unroll
  for (int kk = 0; kk < 4; ++kk) {
    xa[2 * kk]     = *(const float4*)(xr + kk * 32);
    xa[2 * kk + 1] = *(const float4*)(xr + kk * 32 + 4);
  }

  // ---- 3) stage w -> Wb (bf16, swizzled) ----
  #pragma unroll
  for (int j = 0; j < 3; ++j) {
    const int i4 = j * 1024 + tid * 4;     // i = k*1024 + c*8 + f
    const int k = i4 >> 10, c = (i4 >> 3) & 127, f0 = i4 & 7;
    const int q = k * 8 + f0;
    Wb[swzi(q + 0, c)] = (unsigned short)pk2(wv[j].x, wv[j].x);
    Wb[swzi(q + 1, c)] = (unsigned short)pk2(wv[j].y, wv[j].y);
    Wb[swzi(q + 2, c)] = (unsigned short)pk2(wv[j].z, wv[j].z);
    Wb[swzi(q + 3, c)] = (unsigned short)pk2(wv[j].w, wv[j].w);
  }
  { uint2 z = {0u, 0u}; *(uint2*)&Wb[3072 + tid * 4] = z; }  // rows 24..31 = 0
  if (tid < 8) BI[tid] = breg;

  // the ONLY barrier: publish Wb/BI (LDS drain only; x loads stay in flight)
  asm volatile("s_waitcnt lgkmcnt(0)\n\ts_barrier" ::: "memory");

  // ---- 4) x cvt -> A-frags + fp32 row norm ----
  short8v af[4];
  float xn = 0.f;
  #pragma unroll
  for (int kk = 0; kk < 4; ++kk) {
    const float4 a = xa[2 * kk], c4 = xa[2 * kk + 1];
    xn = fmaf(a.x, a.x, fmaf(a.y, a.y, fmaf(a.z, a.z, fmaf(a.w, a.w, xn))));
    xn = fmaf(c4.x, c4.x, fmaf(c4.y, c4.y, fmaf(c4.z, c4.z, fmaf(c4.w, c4.w, xn))));
    uint4 pr;
    pr.x = pk2(a.x, a.y);   pr.y = pk2(a.z, a.w);
    pr.z = pk2(c4.x, c4.y); pr.w = pk2(c4.z, c4.w);
    af[kk] = *(short8v*)&pr;
  }
  xn += __shfl_xor(xn, 16);
  xn += __shfl_xor(xn, 32);   // full |x_row|^2 for row l15, all 4 g-copies

  // ---- 5) B-frags ----
  const int q0 = l15;
  short8v b0f[4], b1f[4];
  #pragma unroll
  for (int kk = 0; kk < 4; ++kk) {
    const int oct = kk * 4 + g;
    b0f[kk] = *(const short8v*)&Wb[swzi(q0,      oct * 8)];
    b1f[kk] = *(const short8v*)&Wb[swzi(q0 + 16, oct * 8)];
  }

  // ---- 6) MFMA: G tiles + WN self-products ----
  f32x4 acc0 = {0.f, 0.f, 0.f, 0.f}, acc1 = {0.f, 0.f, 0.f, 0.f};
  f32x4 aw0  = {0.f, 0.f, 0.f, 0.f}, aw1  = {0.f, 0.f, 0.f, 0.f};
  #pragma unroll
  for (int kk = 0; kk < 4; ++kk) {
    acc0 = __builtin_amdgcn_mfma_f32_16x16x32_bf16(af[kk], b0f[kk], acc0, 0, 0, 0);
    acc1 = __builtin_amdgcn_mfma_f32_16x16x32_bf16(af[kk], b1f[kk], acc1, 0, 0, 0);
    aw0  = __builtin_amdgcn_mfma_f32_16x16x32_bf16(b0f[kk], b0f[kk], aw0, 0, 0, 0);
    aw1  = __builtin_amdgcn_mfma_f32_16x16x32_bf16(b1f[kk], b1f[kk], aw1, 0, 0, 0);
  }

  // ---- 7) WN[q] = diag of aw: value at lane ((q>>2)<<4)|q, reg q&3 ----
  float wn0, wn1;
  {
    const int src = ((l15 >> 2) << 4) | l15;
    const int rsel = l15 & 3;
    float s0 = __shfl(aw0[0], src), s1 = __shfl(aw0[1], src);
    float s2 = __shfl(aw0[2], src), s3 = __shfl(aw0[3], src);
    wn0 = (rsel == 0) ? s0 : (rsel == 1) ? s1 : (rsel == 2) ? s2 : s3;
    s0 = __shfl(aw1[0], src); s1 = __shfl(aw1[1], src);
    s2 = __shfl(aw1[2], src); s3 = __shfl(aw1[3], src);
    wn1 = (rsel == 0) ? s0 : (rsel == 1) ? s1 : (rsel == 2) ? s2 : s3;
  }

  // ---- 8) wave-private (dot,dist) table; C/D: col=lane&15, row=g*4+r [m89] ----
  float* Tw = TB[wave];
  {
    const int rq = g * 4;
    #pragma unroll
    for (int r = 0; r < 4; ++r) {
      const float xnv = __shfl(xn, rq + r);    // norm of local row rq+r
      const int row = rq + r;
      float2 pv0;
      pv0.x = acc0[r];
      pv0.y = sqrtf(fmaxf(xnv + wn0 - 2.f * acc0[r], 0.f));
      *(float2*)&Tw[row * TSTR + q0 * 2] = pv0;
      if (q0 < 8) {
        float2 pv1;
        pv1.x = acc1[r];
        pv1.y = sqrtf(fmaxf(xnv + wn1 - 2.f * acc1[r], 0.f));
        *(float2*)&Tw[row * TSTR + (16 + q0) * 2] = pv1;
      }
    }
  }
  // no barrier: same-wave LDS write->read ordered by lgkmcnt (compiler-emitted)

  // ---- 9) phase 2: lane = (j, f-pair), j in [0,14), within own wave's table ----
  if (lane < WOUT * 4) {
    const int j = lane >> 2, f0 = (lane & 3) * 2;
    const int p = p0 + wave * WOUT + j;

    float d0[3][3], s0[3][3], d1[3][3], s1[3][3];
    #pragma unroll
    for (int i = 0; i < 3; ++i) {
      #pragma unroll
      for (int k = 0; k < 3; ++k) {
        const float4 pr = *(const float4*)&Tw[(j + i) * TSTR + (k * 8 + f0) * 2];
        d0[i][k] = pr.x; s0[i][k] = pr.y;   // f0
        d1[i][k] = pr.z; s1[i][k] = pr.w;   // f0+1
      }
    }

    float2 o;
    {
      const float c11 = s0[0][0];
      const float c12 = c11 + s0[0][1];
      const float c13 = c12 + s0[0][2];
      const float c21 = c11 + s0[1][0];
      const float c31 = c21 + s0[2][0];
      const float A11 = d0[0][0];
      const float A12 = A11 + d0[0][1];
      const float A13 = A12 + d0[0][2];
      const float A21 = A11 + d0[1][0];
      const float A31 = A21 + d0[2][0];
      float c22, A22, c23, A23, c32, A32, cxx, A33;
      dpsel(c11, c21, c12, A11, A21, A12, s0[1][1], d0[1][1], c22, A22);
      dpsel(c12, c22, c13, A12, A22, A13, s0[1][2], d0[1][2], c23, A23);
      dpsel(c21, c31, c22, A21, A31, A22, s0[2][1], d0[2][1], c32, A32);
      dpsel(c22, c32, c23, A22, A32, A23, s0[2][2], d0[2][2], cxx, A33);
      o.x = fmaxf(A33 + BI[f0], 0.f);
    }
    {
      const float c11 = s1[0][0];
      const float c12 = c11 + s1[0][1];
      const float c13 = c12 + s1[0][2];
      const float c21 = c11 + s1[1][0];
      const float c31 = c21 + s1[2][0];
      const float A11 = d1[0][0];
      const float A12 = A11 + d1[0][1];
      const float A13 = A12 + d1[0][2];
      const float A21 = A11 + d1[1][0];
      const float A31 = A21 + d1[2][0];
      float c22, A22, c23, A23, c32, A32, cxx, A33;
      dpsel(c11, c21, c12, A11, A21, A12, s1[1][1], d1[1][1], c22, A22);
      dpsel(c12, c22, c13, A12, A22, A13, s1[1][2], d1[1][2], c23, A23);
      dpsel(c21, c31, c22, A21, A31, A22, s1[2][1], d1[2][1], c32, A32);
      dpsel(c22, c32, c23, A22, A32, A23, s1[2][2], d1[2][2], cxx, A33);
      o.y = fmaxf(A33 + BI[f0 + 1], 0.f);
    }

    if (p < P) *(float2*)&out[((size_t)b * P + p) * 8 + f0] = o;
  }
}

extern "C" void kernel_launch(void* const* d_in, const int* in_sizes, int n_in,
                              void* d_out, int out_size, void* d_ws, size_t ws_size,
                              hipStream_t stream) {
  const float* x    = (const float*)d_in[0];
  const float* w    = (const float*)d_in[1];
  const float* bias = (const float*)d_in[2];
  float* out        = (float*)d_out;

  dim3 grid(37, 32);   // ceil(2046/56) p-tiles x B
  dwa_cnn_kernel<<<grid, 256, 0, stream>>>(x, w, bias, out);
}

// Round 16
// 13.444 us; speedup vs baseline: 1.1273x; 1.0023x over previous
//
#include <hip/hip_runtime.h>

// DWA_CNN: B=32, T=2048, C=128, K=3, F=8, P=2046
// v15: exact revert to v11 (last passing, 13.48us) + one zero-risk reorder:
//      B-frag LDS reads hoisted BEFORE cvt_frags so they retire under the
//      cold-HBM vmcnt wait for xa (shortens the per-wave dependency chain).
//      2-tile pipelining abandoned: v12/v13/v14 all corrupted outputs even
//      with disjoint buffers + full __syncthreads -> mechanism unidentified,
//      EV of a 4th attempt negative.

#define TT    56      // outputs per block = 4 waves * 14
#define WOUT  14      // outputs per wave
#define TSTR  52      // table row stride (floats): 16B-aligned, spreads banks

typedef __attribute__((ext_vector_type(8))) short short8v;
typedef __attribute__((ext_vector_type(4))) float f32x4;

static __device__ inline unsigned pk2(float lo, float hi) {
  unsigned r;
  asm("v_cvt_pk_bf16_f32 %0, %1, %2" : "=v"(r) : "v"(lo), "v"(hi));
  return r;
}
static __device__ inline int swzi(int row, int c) {
  return row * 128 + (((c >> 3) ^ (row & 7)) << 3) + (c & 7);
}

// interior DTW cell; cands order [diag,left,up], first-min tie-break (jnp.argmin)
static __device__ inline void dpsel(float ca, float cb, float cc,
                                    float Ad, float Al, float Au,
                                    float dist, float dot,
                                    float& costv, float& Av) {
  costv = dist + fminf(fminf(ca, cb), cc);
  const bool d_le_l = (ca <= cb);
  const bool d_le_u = (ca <= cc);
  const bool l_le_u = (cb <= cc);
  Av = dot + (d_le_l ? (d_le_u ? Ad : Au) : (l_le_u ? Al : Au));
}

__global__ __launch_bounds__(256, 4) void dwa_cnn_kernel(
    const float* __restrict__ x, const float* __restrict__ w,
    const float* __restrict__ bias, float* __restrict__ out)
{
  constexpr int T = 2048, C = 128, P = 2046;

  __shared__ alignas(16) unsigned short Wb[32 * 128];   // 8 KB (rows 24..31 zero)
  __shared__ alignas(16) float TB[4][16 * TSTR];        // 13.3 KB wave-private tables
  __shared__ float BI[8];

  const int tid  = threadIdx.x;
  const int b    = blockIdx.y;
  const int p0   = blockIdx.x * TT;
  const int wave = tid >> 6;
  const int lane = tid & 63;
  const int g    = lane >> 4, l15 = lane & 15;

  // this wave's global row for the A-fragment (clamped; excess outputs masked)
  const int trow0 = p0 + wave * WOUT + l15;
  const int trow  = (trow0 < T) ? trow0 : (T - 1);

  // ---- 1) w loads first (oldest in vmcnt queue) ----
  float4 wv[3];
  #pragma unroll
  for (int j = 0; j < 3; ++j)
    wv[j] = *(const float4*)&w[j * 1024 + tid * 4];
  const float breg = (tid < 8) ? bias[tid] : 0.f;

  // ---- 2) x loads (8 dwordx4, 2 contiguous per k-step) ----
  const float* xr = &x[((size_t)b * T + trow) * C + g * 8];
  float4 xa[8];
  #pragma unroll
  for (int kk = 0; kk < 4; ++kk) {
    xa[2 * kk]     = *(const float4*)(xr + kk * 32);
    xa[2 * kk + 1] = *(const float4*)(xr + kk * 32 + 4);
  }

  // ---- 3) stage w -> Wb (bf16, swizzled) ----
  #pragma unroll
  for (int j = 0; j < 3; ++j) {
    const int i4 = j * 1024 + tid * 4;     // i = k*1024 + c*8 + f
    const int k = i4 >> 10, c = (i4 >> 3) & 127, f0 = i4 & 7;
    const int q = k * 8 + f0;
    Wb[swzi(q + 0, c)] = (unsigned short)pk2(wv[j].x, wv[j].x);
    Wb[swzi(q + 1, c)] = (unsigned short)pk2(wv[j].y, wv[j].y);
    Wb[swzi(q + 2, c)] = (unsigned short)pk2(wv[j].z, wv[j].z);
    Wb[swzi(q + 3, c)] = (unsigned short)pk2(wv[j].w, wv[j].w);
  }
  { uint2 z = {0u, 0u}; *(uint2*)&Wb[3072 + tid * 4] = z; }  // rows 24..31 = 0
  if (tid < 8) BI[tid] = breg;

  // the ONLY barrier: publish Wb/BI (LDS drain only; x loads stay in flight)
  asm volatile("s_waitcnt lgkmcnt(0)\n\ts_barrier" ::: "memory");

  // ---- 4) B-frags FIRST (LDS-only; retire under the xa vmcnt wait) ----
  const int q0 = l15;
  short8v b0f[4], b1f[4];
  #pragma unroll
  for (int kk = 0; kk < 4; ++kk) {
    const int oct = kk * 4 + g;
    b0f[kk] = *(const short8v*)&Wb[swzi(q0,      oct * 8)];
    b1f[kk] = *(const short8v*)&Wb[swzi(q0 + 16, oct * 8)];
  }

  // ---- 5) x cvt -> A-frags + fp32 row norm (waits on xa here) ----
  short8v af[4];
  float xn = 0.f;
  #pragma unroll
  for (int kk = 0; kk < 4; ++kk) {
    const float4 a = xa[2 * kk], c4 = xa[2 * kk + 1];
    xn = fmaf(a.x, a.x, fmaf(a.y, a.y, fmaf(a.z, a.z, fmaf(a.w, a.w, xn))));
    xn = fmaf(c4.x, c4.x, fmaf(c4.y, c4.y, fmaf(c4.z, c4.z, fmaf(c4.w, c4.w, xn))));
    uint4 pr;
    pr.x = pk2(a.x, a.y);   pr.y = pk2(a.z, a.w);
    pr.z = pk2(c4.x, c4.y); pr.w = pk2(c4.z, c4.w);
    af[kk] = *(short8v*)&pr;
  }
  xn += __shfl_xor(xn, 16);
  xn += __shfl_xor(xn, 32);   // full |x_row|^2 for row l15, all 4 g-copies

  // ---- 6) MFMA: G tiles + WN self-products ----
  f32x4 acc0 = {0.f, 0.f, 0.f, 0.f}, acc1 = {0.f, 0.f, 0.f, 0.f};
  f32x4 aw0  = {0.f, 0.f, 0.f, 0.f}, aw1  = {0.f, 0.f, 0.f, 0.f};
  #pragma unroll
  for (int kk = 0; kk < 4; ++kk) {
    acc0 = __builtin_amdgcn_mfma_f32_16x16x32_bf16(af[kk], b0f[kk], acc0, 0, 0, 0);
    acc1 = __builtin_amdgcn_mfma_f32_16x16x32_bf16(af[kk], b1f[kk], acc1, 0, 0, 0);
    aw0  = __builtin_amdgcn_mfma_f32_16x16x32_bf16(b0f[kk], b0f[kk], aw0, 0, 0, 0);
    aw1  = __builtin_amdgcn_mfma_f32_16x16x32_bf16(b1f[kk], b1f[kk], aw1, 0, 0, 0);
  }

  // ---- 7) WN[q] = diag of aw: value at lane ((q>>2)<<4)|q, reg q&3 ----
  float wn0, wn1;
  {
    const int src = ((l15 >> 2) << 4) | l15;
    const int rsel = l15 & 3;
    float s0 = __shfl(aw0[0], src), s1 = __shfl(aw0[1], src);
    float s2 = __shfl(aw0[2], src), s3 = __shfl(aw0[3], src);
    wn0 = (rsel == 0) ? s0 : (rsel == 1) ? s1 : (rsel == 2) ? s2 : s3;
    s0 = __shfl(aw1[0], src); s1 = __shfl(aw1[1], src);
    s2 = __shfl(aw1[2], src); s3 = __shfl(aw1[3], src);
    wn1 = (rsel == 0) ? s0 : (rsel == 1) ? s1 : (rsel == 2) ? s2 : s3;
  }

  // ---- 8) wave-private (dot,dist) table; C/D: col=lane&15, row=g*4+r [m89] ----
  float* Tw = TB[wave];
  {
    const int rq = g * 4;
    #pragma unroll
    for (int r = 0; r < 4; ++r) {
      const float xnv = __shfl(xn, rq + r);    // norm of local row rq+r
      const int row = rq + r;
      float2 pv0;
      pv0.x = acc0[r];
      pv0.y = sqrtf(fmaxf(xnv + wn0 - 2.f * acc0[r], 0.f));
      *(float2*)&Tw[row * TSTR + q0 * 2] = pv0;
      if (q0 < 8) {
        float2 pv1;
        pv1.x = acc1[r];
        pv1.y = sqrtf(fmaxf(xnv + wn1 - 2.f * acc1[r], 0.f));
        *(float2*)&Tw[row * TSTR + (16 + q0) * 2] = pv1;
      }
    }
  }
  // no barrier: same-wave LDS write->read ordered by lgkmcnt (compiler-emitted)

  // ---- 9) phase 2: lane = (j, f-pair), j in [0,14), within own wave's table ----
  if (lane < WOUT * 4) {
    const int j = lane >> 2, f0 = (lane & 3) * 2;
    const int p = p0 + wave * WOUT + j;

    float d0[3][3], s0[3][3], d1[3][3], s1[3][3];
    #pragma unroll
    for (int i = 0; i < 3; ++i) {
      #pragma unroll
      for (int k = 0; k < 3; ++k) {
        const float4 pr = *(const float4*)&Tw[(j + i) * TSTR + (k * 8 + f0) * 2];
        d0[i][k] = pr.x; s0[i][k] = pr.y;   // f0
        d1[i][k] = pr.z; s1[i][k] = pr.w;   // f0+1
      }
    }

    float2 o;
    {
      const float c11 = s0[0][0];
      const float c12 = c11 + s0[0][1];
      const float c13 = c12 + s0[0][2];
      const float c21 = c11 + s0[1][0];
      const float c31 = c21 + s0[2][0];
      const float A11 = d0[0][0];
      const float A12 = A11 + d0[0][1];
      const float A13 = A12 + d0[0][2];
      const float A21 = A11 + d0[1][0];
      const float A31 = A21 + d0[2][0];
      float c22, A22, c23, A23, c32, A32, cxx, A33;
      dpsel(c11, c21, c12, A11, A21, A12, s0[1][1], d0[1][1], c22, A22);
      dpsel(c12, c22, c13, A12, A22, A13, s0[1][2], d0[1][2], c23, A23);
      dpsel(c21, c31, c22, A21, A31, A22, s0[2][1], d0[2][1], c32, A32);
      dpsel(c22, c32, c23, A22, A32, A23, s0[2][2], d0[2][2], cxx, A33);
      o.x = fmaxf(A33 + BI[f0], 0.f);
    }
    {
      const float c11 = s1[0][0];
      const float c12 = c11 + s1[0][1];
      const float c13 = c12 + s1[0][2];
      const float c21 = c11 + s1[1][0];
      const float c31 = c21 + s1[2][0];
      const float A11 = d1[0][0];
      const float A12 = A11 + d1[0][1];
      const float A13 = A12 + d1[0][2];
      const float A21 = A11 + d1[1][0];
      const float A31 = A21 + d1[2][0];
      float c22, A22, c23, A23, c32, A32, cxx, A33;
      dpsel(c11, c21, c12, A11, A21, A12, s1[1][1], d1[1][1], c22, A22);
      dpsel(c12, c22, c13, A12, A22, A13, s1[1][2], d1[1][2], c23, A23);
      dpsel(c21, c31, c22, A21, A31, A22, s1[2][1], d1[2][1], c32, A32);
      dpsel(c22, c32, c23, A22, A32, A23, s1[2][2], d1[2][2], cxx, A33);
      o.y = fmaxf(A33 + BI[f0 + 1], 0.f);
    }

    if (p < P) *(float2*)&out[((size_t)b * P + p) * 8 + f0] = o;
  }
}

extern "C" void kernel_launch(void* const* d_in, const int* in_sizes, int n_in,
                              void* d_out, int out_size, void* d_ws, size_t ws_size,
                              hipStream_t stream) {
  const float* x    = (const float*)d_in[0];
  const float* w    = (const float*)d_in[1];
  const float* bias = (const float*)d_in[2];
  float* out        = (float*)d_out;

  dim3 grid(37, 32);   // ceil(2046/56) p-tiles x B
  dwa_cnn_kernel<<<grid, 256, 0, stream>>>(x, w, bias, out);
}

// Round 17
// 13.360 us; speedup vs baseline: 1.1344x; 1.0063x over previous
//
#include <hip/hip_runtime.h>

// DWA_CNN: B=32, T=2048, C=128, K=3, F=8, P=2046
// v16: v15 (13.44us, passed) with __launch_bounds__(256,5): grid=1184 blocks,
//      4/CU residency left a 160-block serial tail round (~1-1.5us exposed
//      chain); 5/CU -> 1280 slots >= 1184 -> ALL blocks co-resident, tail
//      eliminated, 20 waves/CU latency hiding. VGPR cap 102 proven safe by v8
//      (same phase-1 body at (256,5), passed). Everything else identical.

#define TT    56      // outputs per block = 4 waves * 14
#define WOUT  14      // outputs per wave
#define TSTR  52      // table row stride (floats): 16B-aligned, spreads banks

typedef __attribute__((ext_vector_type(8))) short short8v;
typedef __attribute__((ext_vector_type(4))) float f32x4;

static __device__ inline unsigned pk2(float lo, float hi) {
  unsigned r;
  asm("v_cvt_pk_bf16_f32 %0, %1, %2" : "=v"(r) : "v"(lo), "v"(hi));
  return r;
}
static __device__ inline int swzi(int row, int c) {
  return row * 128 + (((c >> 3) ^ (row & 7)) << 3) + (c & 7);
}

// interior DTW cell; cands order [diag,left,up], first-min tie-break (jnp.argmin)
static __device__ inline void dpsel(float ca, float cb, float cc,
                                    float Ad, float Al, float Au,
                                    float dist, float dot,
                                    float& costv, float& Av) {
  costv = dist + fminf(fminf(ca, cb), cc);
  const bool d_le_l = (ca <= cb);
  const bool d_le_u = (ca <= cc);
  const bool l_le_u = (cb <= cc);
  Av = dot + (d_le_l ? (d_le_u ? Ad : Au) : (l_le_u ? Al : Au));
}

__global__ __launch_bounds__(256, 5) void dwa_cnn_kernel(
    const float* __restrict__ x, const float* __restrict__ w,
    const float* __restrict__ bias, float* __restrict__ out)
{
  constexpr int T = 2048, C = 128, P = 2046;

  __shared__ alignas(16) unsigned short Wb[32 * 128];   // 8 KB (rows 24..31 zero)
  __shared__ alignas(16) float TB[4][16 * TSTR];        // 13.3 KB wave-private tables
  __shared__ float BI[8];

  const int tid  = threadIdx.x;
  const int b    = blockIdx.y;
  const int p0   = blockIdx.x * TT;
  const int wave = tid >> 6;
  const int lane = tid & 63;
  const int g    = lane >> 4, l15 = lane & 15;

  // this wave's global row for the A-fragment (clamped; excess outputs masked)
  const int trow0 = p0 + wave * WOUT + l15;
  const int trow  = (trow0 < T) ? trow0 : (T - 1);

  // ---- 1) w loads first (oldest in vmcnt queue) ----
  float4 wv[3];
  #pragma unroll
  for (int j = 0; j < 3; ++j)
    wv[j] = *(const float4*)&w[j * 1024 + tid * 4];
  const float breg = (tid < 8) ? bias[tid] : 0.f;

  // ---- 2) x loads (8 dwordx4, 2 contiguous per k-step) ----
  const float* xr = &x[((size_t)b * T + trow) * C + g * 8];
  float4 xa[8];
  #pragma unroll
  for (int kk = 0; kk < 4; ++kk) {
    xa[2 * kk]     = *(const float4*)(xr + kk * 32);
    xa[2 * kk + 1] = *(const float4*)(xr + kk * 32 + 4);
  }

  // ---- 3) stage w -> Wb (bf16, swizzled) ----
  #pragma unroll
  for (int j = 0; j < 3; ++j) {
    const int i4 = j * 1024 + tid * 4;     // i = k*1024 + c*8 + f
    const int k = i4 >> 10, c = (i4 >> 3) & 127, f0 = i4 & 7;
    const int q = k * 8 + f0;
    Wb[swzi(q + 0, c)] = (unsigned short)pk2(wv[j].x, wv[j].x);
    Wb[swzi(q + 1, c)] = (unsigned short)pk2(wv[j].y, wv[j].y);
    Wb[swzi(q + 2, c)] = (unsigned short)pk2(wv[j].z, wv[j].z);
    Wb[swzi(q + 3, c)] = (unsigned short)pk2(wv[j].w, wv[j].w);
  }
  { uint2 z = {0u, 0u}; *(uint2*)&Wb[3072 + tid * 4] = z; }  // rows 24..31 = 0
  if (tid < 8) BI[tid] = breg;

  // the ONLY barrier: publish Wb/BI (LDS drain only; x loads stay in flight)
  asm volatile("s_waitcnt lgkmcnt(0)\n\ts_barrier" ::: "memory");

  // ---- 4) B-frags FIRST (LDS-only; retire under the xa vmcnt wait) ----
  const int q0 = l15;
  short8v b0f[4], b1f[4];
  #pragma unroll
  for (int kk = 0; kk < 4; ++kk) {
    const int oct = kk * 4 + g;
    b0f[kk] = *(const short8v*)&Wb[swzi(q0,      oct * 8)];
    b1f[kk] = *(const short8v*)&Wb[swzi(q0 + 16, oct * 8)];
  }

  // ---- 5) x cvt -> A-frags + fp32 row norm (waits on xa here) ----
  short8v af[4];
  float xn = 0.f;
  #pragma unroll
  for (int kk = 0; kk < 4; ++kk) {
    const float4 a = xa[2 * kk], c4 = xa[2 * kk + 1];
    xn = fmaf(a.x, a.x, fmaf(a.y, a.y, fmaf(a.z, a.z, fmaf(a.w, a.w, xn))));
    xn = fmaf(c4.x, c4.x, fmaf(c4.y, c4.y, fmaf(c4.z, c4.z, fmaf(c4.w, c4.w, xn))));
    uint4 pr;
    pr.x = pk2(a.x, a.y);   pr.y = pk2(a.z, a.w);
    pr.z = pk2(c4.x, c4.y); pr.w = pk2(c4.z, c4.w);
    af[kk] = *(short8v*)&pr;
  }
  xn += __shfl_xor(xn, 16);
  xn += __shfl_xor(xn, 32);   // full |x_row|^2 for row l15, all 4 g-copies

  // ---- 6) MFMA: G tiles + WN self-products ----
  f32x4 acc0 = {0.f, 0.f, 0.f, 0.f}, acc1 = {0.f, 0.f, 0.f, 0.f};
  f32x4 aw0  = {0.f, 0.f, 0.f, 0.f}, aw1  = {0.f, 0.f, 0.f, 0.f};
  #pragma unroll
  for (int kk = 0; kk < 4; ++kk) {
    acc0 = __builtin_amdgcn_mfma_f32_16x16x32_bf16(af[kk], b0f[kk], acc0, 0, 0, 0);
    acc1 = __builtin_amdgcn_mfma_f32_16x16x32_bf16(af[kk], b1f[kk], acc1, 0, 0, 0);
    aw0  = __builtin_amdgcn_mfma_f32_16x16x32_bf16(b0f[kk], b0f[kk], aw0, 0, 0, 0);
    aw1  = __builtin_amdgcn_mfma_f32_16x16x32_bf16(b1f[kk], b1f[kk], aw1, 0, 0, 0);
  }

  // ---- 7) WN[q] = diag of aw: value at lane ((q>>2)<<4)|q, reg q&3 ----
  float wn0, wn1;
  {
    const int src = ((l15 >> 2) << 4) | l15;
    const int rsel = l15 & 3;
    float s0 = __shfl(aw0[0], src), s1 = __shfl(aw0[1], src);
    float s2 = __shfl(aw0[2], src), s3 = __shfl(aw0[3], src);
    wn0 = (rsel == 0) ? s0 : (rsel == 1) ? s1 : (rsel == 2) ? s2 : s3;
    s0 = __shfl(aw1[0], src); s1 = __shfl(aw1[1], src);
    s2 = __shfl(aw1[2], src); s3 = __shfl(aw1[3], src);
    wn1 = (rsel == 0) ? s0 : (rsel == 1) ? s1 : (rsel == 2) ? s2 : s3;
  }

  // ---- 8) wave-private (dot,dist) table; C/D: col=lane&15, row=g*4+r [m89] ----
  float* Tw = TB[wave];
  {
    const int rq = g * 4;
    #pragma unroll
    for (int r = 0; r < 4; ++r) {
      const float xnv = __shfl(xn, rq + r);    // norm of local row rq+r
      const int row = rq + r;
      float2 pv0;
      pv0.x = acc0[r];
      pv0.y = sqrtf(fmaxf(xnv + wn0 - 2.f * acc0[r], 0.f));
      *(float2*)&Tw[row * TSTR + q0 * 2] = pv0;
      if (q0 < 8) {
        float2 pv1;
        pv1.x = acc1[r];
        pv1.y = sqrtf(fmaxf(xnv + wn1 - 2.f * acc1[r], 0.f));
        *(float2*)&Tw[row * TSTR + (16 + q0) * 2] = pv1;
      }
    }
  }
  // no barrier: same-wave LDS write->read ordered by lgkmcnt (compiler-emitted)

  // ---- 9) phase 2: lane = (j, f-pair), j in [0,14), within own wave's table ----
  if (lane < WOUT * 4) {
    const int j = lane >> 2, f0 = (lane & 3) * 2;
    const int p = p0 + wave * WOUT + j;

    float d0[3][3], s0[3][3], d1[3][3], s1[3][3];
    #pragma unroll
    for (int i = 0; i < 3; ++i) {
      #pragma unroll
      for (int k = 0; k < 3; ++k) {
        const float4 pr = *(const float4*)&Tw[(j + i) * TSTR + (k * 8 + f0) * 2];
        d0[i][k] = pr.x; s0[i][k] = pr.y;   // f0
        d1[i][k] = pr.z; s1[i][k] = pr.w;   // f0+1
      }
    }

    float2 o;
    {
      const float c11 = s0[0][0];
      const float c12 = c11 + s0[0][1];
      const float c13 = c12 + s0[0][2];
      const float c21 = c11 + s0[1][0];
      const float c31 = c21 + s0[2][0];
      const float A11 = d0[0][0];
      const float A12 = A11 + d0[0][1];
      const float A13 = A12 + d0[0][2];
      const float A21 = A11 + d0[1][0];
      const float A31 = A21 + d0[2][0];
      float c22, A22, c23, A23, c32, A32, cxx, A33;
      dpsel(c11, c21, c12, A11, A21, A12, s0[1][1], d0[1][1], c22, A22);
      dpsel(c12, c22, c13, A12, A22, A13, s0[1][2], d0[1][2], c23, A23);
      dpsel(c21, c31, c22, A21, A31, A22, s0[2][1], d0[2][1], c32, A32);
      dpsel(c22, c32, c23, A22, A32, A23, s0[2][2], d0[2][2], cxx, A33);
      o.x = fmaxf(A33 + BI[f0], 0.f);
    }
    {
      const float c11 = s1[0][0];
      const float c12 = c11 + s1[0][1];
      const float c13 = c12 + s1[0][2];
      const float c21 = c11 + s1[1][0];
      const float c31 = c21 + s1[2][0];
      const float A11 = d1[0][0];
      const float A12 = A11 + d1[0][1];
      const float A13 = A12 + d1[0][2];
      const float A21 = A11 + d1[1][0];
      const float A31 = A21 + d1[2][0];
      float c22, A22, c23, A23, c32, A32, cxx, A33;
      dpsel(c11, c21, c12, A11, A21, A12, s1[1][1], d1[1][1], c22, A22);
      dpsel(c12, c22, c13, A12, A22, A13, s1[1][2], d1[1][2], c23, A23);
      dpsel(c21, c31, c22, A21, A31, A22, s1[2][1], d1[2][1], c32, A32);
      dpsel(c22, c32, c23, A22, A32, A23, s1[2][2], d1[2][2], cxx, A33);
      o.y = fmaxf(A33 + BI[f0 + 1], 0.f);
    }

    if (p < P) *(float2*)&out[((size_t)b * P + p) * 8 + f0] = o;
  }
}

extern "C" void kernel_launch(void* const* d_in, const int* in_sizes, int n_in,
                              void* d_out, int out_size, void* d_ws, size_t ws_size,
                              hipStream_t stream) {
  const float* x    = (const float*)d_in[0];
  const float* w    = (const float*)d_in[1];
  const float* bias = (const float*)d_in[2];
  float* out        = (float*)d_out;

  dim3 grid(37, 32);   // ceil(2046/56) p-tiles x B; 1184 blocks, all resident at 5/CU
  dwa_cnn_kernel<<<grid, 256, 0, stream>>>(x, w, bias, out);
}